// Round 3
// baseline (485.709 us; speedup 1.0000x reference)
//
#include <hip/hip_runtime.h>
#include <hip/hip_bf16.h>
#include <stdint.h>

typedef unsigned short u16;

#define NINF (-__builtin_huge_valf())

__device__ __forceinline__ u16 f2bf(float f) {
    unsigned int u = __float_as_uint(f);
    u += 0x7FFFu + ((u >> 16) & 1u);   // round-to-nearest-even
    return (u16)(u >> 16);
}
__device__ __forceinline__ void unpack8(uint4 u, float* f) {
    f[0] = __uint_as_float(u.x << 16);
    f[1] = __uint_as_float(u.x & 0xFFFF0000u);
    f[2] = __uint_as_float(u.y << 16);
    f[3] = __uint_as_float(u.y & 0xFFFF0000u);
    f[4] = __uint_as_float(u.z << 16);
    f[5] = __uint_as_float(u.z & 0xFFFF0000u);
    f[6] = __uint_as_float(u.w << 16);
    f[7] = __uint_as_float(u.w & 0xFFFF0000u);
}
__device__ __forceinline__ void unpack4(uint2 u, float* f) {
    f[0] = __uint_as_float(u.x << 16);
    f[1] = __uint_as_float(u.x & 0xFFFF0000u);
    f[2] = __uint_as_float(u.y << 16);
    f[3] = __uint_as_float(u.y & 0xFFFF0000u);
}

// ---------------------------------------------------------------------------
// Prologue (fused): blocks [0,256)   -> proj_inv = v_inv @ W_in^T + b_in (bf16)
//                   blocks [256,640) -> proj_equi = v_equi @ W_coord^T  (bf16)
// ---------------------------------------------------------------------------
__global__ __launch_bounds__(256) void k_prologue(
    const float* __restrict__ v_inv,    // [2048, 256]
    const float* __restrict__ W_in,     // [256, 256] (o,i)
    const float* __restrict__ b_in,     // [256]
    u16* __restrict__ proj_inv,         // [2048, 256] bf16
    const float* __restrict__ v_equi,   // [6144, 64] (rows = b*n*3)
    const float* __restrict__ W_coord,  // [64, 64] (o,c)
    u16* __restrict__ proj_equi)        // [6144, 64] bf16
{
    int t = threadIdx.x;
    __shared__ float Xs[8][256];
    __shared__ float Es[16][64];

    if (blockIdx.x < 256) {
        int r0 = blockIdx.x * 8;
#pragma unroll
        for (int i = 0; i < 8; ++i)
            Xs[i][t] = v_inv[(size_t)(r0 + i) * 256 + t];
        __syncthreads();
        float acc[8];
        float bv = b_in[t];
#pragma unroll
        for (int r = 0; r < 8; ++r) acc[r] = bv;
        const float* wrow = W_in + t * 256;
        for (int i = 0; i < 256; i += 4) {
            float4 w = *(const float4*)(wrow + i);
#pragma unroll
            for (int r = 0; r < 8; ++r) {
                acc[r] += Xs[r][i + 0] * w.x;
                acc[r] += Xs[r][i + 1] * w.y;
                acc[r] += Xs[r][i + 2] * w.z;
                acc[r] += Xs[r][i + 3] * w.w;
            }
        }
#pragma unroll
        for (int r = 0; r < 8; ++r)
            proj_inv[(size_t)(r0 + r) * 256 + t] = f2bf(acc[r]);
    } else {
        int bi = blockIdx.x - 256;            // [0,384), 16 rows each
        const float* src = v_equi + (size_t)bi * 1024;
        ((float4*)Es)[t] = *(const float4*)(src + t * 4);
        __syncthreads();
        int o = t & 63, rr = t >> 6;
        float acc[4] = {0.f, 0.f, 0.f, 0.f};
        const float* wrow = W_coord + o * 64;
#pragma unroll
        for (int c = 0; c < 64; c += 4) {
            float4 w = *(const float4*)(wrow + c);
#pragma unroll
            for (int m = 0; m < 4; ++m) {
                int r = rr + 4 * m;
                acc[m] += Es[r][c + 0] * w.x + Es[r][c + 1] * w.y
                        + Es[r][c + 2] * w.z + Es[r][c + 3] * w.w;
            }
        }
        u16* dst = proj_equi + (size_t)bi * 1024;
#pragma unroll
        for (int m = 0; m < 4; ++m)
            dst[(rr + 4 * m) * 64 + o] = f2bf(acc[m]);
    }
}

// ---------------------------------------------------------------------------
// Fused attention kernel.
//   blocks [0,2048)    : equi attention, one (b,q) per block
//                        (kk-reduction now via __shfl_xor butterfly: LDS 25KB->5KB)
//   blocks [2048,4096) : inv attention, one (b,q) per block + fused W_out GEMV
// Union LDS = 22160 B -> 7 blocks/CU (28/32 waves). __launch_bounds__(256,7)
// keeps VGPR <= ~72 so occupancy is LDS-limited, not VGPR-limited.
// ---------------------------------------------------------------------------
struct SmemEqui {
    float maskv[256];
    int   anyflag;
    int   pad[3];
    float wp[4][5][64];     // per-wave partials: s, s2, a0, a1, a2
    float out_s[3][64];
};
struct SmemInv {
    float maskv[256];
    int   anyflag;
    int   pad[3];
    float p_s[256][16];
    float sh_sp[4][16];
    float sh_s2p[4][16];
    float sh_s[16];
    float sh_s2[16];
    float red[4][256];      // red[0] is reused for the scaled out_i vector
};
union SmemU {
    SmemEqui e;
    SmemInv  i;
};

__global__ __launch_bounds__(256, 7) void k_fused_attn(
    const float* __restrict__ equi_msg,  // [B,256,256,64] fp32
    const float* __restrict__ inv_msg,   // [B,256,256,16] fp32
    const int* __restrict__ adj,         // [B,256,256]
    const u16* __restrict__ proj_equi,   // [B,256,3,64] bf16 (ws)
    const u16* __restrict__ proj_inv,    // [B,256,256] bf16 (ws)
    const float* __restrict__ W_eo,      // [64,64] (o,c)
    const float* __restrict__ b_eo,      // [64]
    const float* __restrict__ W_out,     // [256,256] (o,i)
    const float* __restrict__ b_out,     // [256]
    float* __restrict__ out)             // equi: [B,256,3,64] then inv: [B,256,256]
{
    __shared__ SmemU S;
    int t = threadIdx.x;

    if (blockIdx.x < 2048) {
        // ================= equi path =================
        int bq = blockIdx.x;
        int b = bq >> 8;

        if (t == 0) S.e.anyflag = 0;
        __syncthreads();
        int a = adj[(size_t)bq * 256 + t];
        if (a != 0) S.e.anyflag = 1;
        __syncthreads();
        S.e.maskv[t] = (a == 0 && S.e.anyflag != 0) ? NINF : 0.0f;
        __syncthreads();

        int kk = t >> 3;            // [0,32): k-group; within a wave = lane bits 3..5
        int c0 = (t & 7) * 8;       // channel group start
        float s[8], s2[8], a0[8], a1[8], a2[8];
#pragma unroll
        for (int u = 0; u < 8; ++u) { s[u] = 0.f; s2[u] = 0.f; a0[u] = 0.f; a1[u] = 0.f; a2[u] = 0.f; }

        const float* msg_base = equi_msg + (size_t)bq * 16384;
        const u16* proj_base = proj_equi + (size_t)b * 49152;
        const float* mrow = msg_base + kk * 64 + c0;    // stride per j: 32 rows * 64 = 2048 floats

        // 1-deep software prefetch on the long-latency msg stream
        float4 cur0 = *(const float4*)(mrow);
        float4 cur1 = *(const float4*)(mrow + 4);
#pragma unroll
        for (int j = 0; j < 8; ++j) {
            float4 nx0 = cur0, nx1 = cur1;
            if (j < 7) {
                nx0 = *(const float4*)(mrow + (j + 1) * 2048);
                nx1 = *(const float4*)(mrow + (j + 1) * 2048 + 4);
            }
            int k = kk + 32 * j;
            float m = S.e.maskv[k];
            const u16* pb = proj_base + k * 192 + c0;
            uint4 up0 = *(const uint4*)(pb);
            uint4 up1 = *(const uint4*)(pb + 64);
            uint4 up2 = *(const uint4*)(pb + 128);
            float mv[8], p0[8], p1[8], p2[8];
            mv[0] = cur0.x; mv[1] = cur0.y; mv[2] = cur0.z; mv[3] = cur0.w;
            mv[4] = cur1.x; mv[5] = cur1.y; mv[6] = cur1.z; mv[7] = cur1.w;
            unpack8(up0, p0); unpack8(up1, p1); unpack8(up2, p2);
#pragma unroll
            for (int u = 0; u < 8; ++u) {
                float e = __expf(mv[u] + m);
                s[u] += e;
                s2[u] += e * e;
                a0[u] += e * p0[u];
                a1[u] += e * p1[u];
                a2[u] += e * p2[u];
            }
            cur0 = nx0; cur1 = nx1;
        }

        // ---- reduce over kk: butterfly across lane bits 3..5 (8 kk per wave)
#pragma unroll
        for (int msk = 8; msk <= 32; msk <<= 1) {
#pragma unroll
            for (int u = 0; u < 8; ++u) {
                s[u]  += __shfl_xor(s[u],  msk);
                s2[u] += __shfl_xor(s2[u], msk);
                a0[u] += __shfl_xor(a0[u], msk);
                a1[u] += __shfl_xor(a1[u], msk);
                a2[u] += __shfl_xor(a2[u], msk);
            }
        }
        {
            int w = t >> 6;
            if ((t & 63) < 8) {     // lane l<8 holds wave-sum for c = l*8..l*8+7
#pragma unroll
                for (int u = 0; u < 8; ++u) {
                    S.e.wp[w][0][c0 + u] = s[u];
                    S.e.wp[w][1][c0 + u] = s2[u];
                    S.e.wp[w][2][c0 + u] = a0[u];
                    S.e.wp[w][3][c0 + u] = a1[u];
                    S.e.wp[w][4][c0 + u] = a2[u];
                }
            }
        }
        __syncthreads();
        if (t < 192) {
            int d = t >> 6, c = t & 63;
            float ssum = 0.f, s2sum = 0.f, asum = 0.f;
#pragma unroll
            for (int w = 0; w < 4; ++w) {
                ssum  += S.e.wp[w][0][c];
                s2sum += S.e.wp[w][1][c];
                asum  += S.e.wp[w][2 + d][c];
            }
            float scale = sqrtf(s2sum) / (ssum * ssum);
            S.e.out_s[d][c] = asum * scale;
        }
        __syncthreads();
        if (t < 192) {
            int d = t >> 6, o = t & 63;
            float acc = b_eo[o];
            const float* wr = W_eo + o * 64;
#pragma unroll
            for (int c4 = 0; c4 < 64; c4 += 4) {
                float4 w = *(const float4*)(wr + c4);
                acc += S.e.out_s[d][c4 + 0] * w.x;
                acc += S.e.out_s[d][c4 + 1] * w.y;
                acc += S.e.out_s[d][c4 + 2] * w.z;
                acc += S.e.out_s[d][c4 + 3] * w.w;
            }
            out[(size_t)bq * 192 + t] = acc;
        }
    } else {
        // ================= inv path: one (b,q) per block =================
        int bq = blockIdx.x - 2048;
        int b = bq >> 8;

        if (t == 0) S.i.anyflag = 0;
        __syncthreads();
        int a = adj[(size_t)bq * 256 + t];
        if (a != 0) S.i.anyflag = 1;
        __syncthreads();
        S.i.maskv[t] = (a == 0 && S.i.anyflag != 0) ? NINF : 0.0f;
        __syncthreads();

        // ---- pass 1: exps (float4 over 4 heads) + s/s2 via shuffle butterfly
        {
            int hq = t & 3;            // head quad: h = hq*4 .. hq*4+3
            int kkg = t >> 2;          // [0,64)
            const float* mb = inv_msg + (size_t)bq * 4096;
            float ss[4] = {0.f, 0.f, 0.f, 0.f};
            float ss2[4] = {0.f, 0.f, 0.f, 0.f};
#pragma unroll
            for (int j = 0; j < 4; ++j) {
                int k = kkg + 64 * j;
                float4 v = *(const float4*)(mb + k * 16 + hq * 4);
                float mval = S.i.maskv[k];
                float e0 = __expf(v.x + mval);
                float e1 = __expf(v.y + mval);
                float e2 = __expf(v.z + mval);
                float e3 = __expf(v.w + mval);
                *(float4*)(&S.i.p_s[k][hq * 4]) = make_float4(e0, e1, e2, e3);
                ss[0] += e0; ss[1] += e1; ss[2] += e2; ss[3] += e3;
                ss2[0] += e0 * e0; ss2[1] += e1 * e1;
                ss2[2] += e2 * e2; ss2[3] += e3 * e3;
            }
            // lane = (kkg&15)*4 + hq; reduce over the 16 k-groups of this wave
#pragma unroll
            for (int m = 4; m <= 32; m <<= 1) {
#pragma unroll
                for (int i = 0; i < 4; ++i) {
                    ss[i]  += __shfl_xor(ss[i], m);
                    ss2[i] += __shfl_xor(ss2[i], m);
                }
            }
            if ((t & 63) < 4) {
                int w = t >> 6;
                *(float4*)(&S.i.sh_sp[w][hq * 4])  = make_float4(ss[0], ss[1], ss[2], ss[3]);
                *(float4*)(&S.i.sh_s2p[w][hq * 4]) = make_float4(ss2[0], ss2[1], ss2[2], ss2[3]);
            }
        }
        __syncthreads();
        if (t < 32) {
            int sel = t >> 4, h = t & 15;
            if (sel == 0)
                S.i.sh_s[h] = S.i.sh_sp[0][h] + S.i.sh_sp[1][h]
                            + S.i.sh_sp[2][h] + S.i.sh_sp[3][h];
            else
                S.i.sh_s2[h] = S.i.sh_s2p[0][h] + S.i.sh_s2p[1][h]
                             + S.i.sh_s2p[2][h] + S.i.sh_s2p[3][h];
        }
        __syncthreads();

        // ---- pass 2: out_i[h,e] = sum_k p[k,h] * proj[b,k,h*16+e]
        {
            int kk2 = t >> 6, h = (t >> 2) & 15, eg = t & 3;
            float acc[4] = {0.f, 0.f, 0.f, 0.f};
            const u16* pb = proj_inv + (size_t)b * 65536 + h * 16 + eg * 4;
#pragma unroll 8
            for (int j = 0; j < 64; ++j) {
                int k = kk2 + 4 * j;
                uint2 u = *(const uint2*)(pb + (size_t)k * 256);
                float w[4]; unpack4(u, w);
                float p = S.i.p_s[k][h];
#pragma unroll
                for (int ii = 0; ii < 4; ++ii) acc[ii] += p * w[ii];
            }
#pragma unroll
            for (int ii = 0; ii < 4; ++ii)
                S.i.red[kk2][h * 16 + eg * 4 + ii] = acc[ii];
        }
        __syncthreads();
        {
            // thread t only reads column t, then overwrites red[0][t]: no race
            int h = t >> 4;
            float sum = S.i.red[0][t] + S.i.red[1][t] + S.i.red[2][t] + S.i.red[3][t];
            float sv = S.i.sh_s[h];
            S.i.red[0][t] = sum * sqrtf(S.i.sh_s2[h]) / (sv * sv);
        }
        __syncthreads();

        // ---- fused epilogue: inv_updates[bq,o] = b_out[o] + out_i . W_out[o,:]
        {
            float acc = b_out[t];
            const float* wrow = W_out + t * 256;
#pragma unroll 8
            for (int i = 0; i < 256; i += 4) {
                float4 w = *(const float4*)(wrow + i);
                acc += S.i.red[0][i + 0] * w.x;
                acc += S.i.red[0][i + 1] * w.y;
                acc += S.i.red[0][i + 2] * w.z;
                acc += S.i.red[0][i + 3] * w.w;
            }
            out[393216 + (size_t)bq * 256 + t] = acc;
        }
    }
}

// ---------------------------------------------------------------------------
extern "C" void kernel_launch(void* const* d_in, const int* in_sizes, int n_in,
                              void* d_out, int out_size, void* d_ws, size_t ws_size,
                              hipStream_t stream) {
    (void)in_sizes; (void)n_in; (void)out_size; (void)ws_size;

    const float* v_equi   = (const float*)d_in[0];
    const float* v_inv    = (const float*)d_in[1];
    const float* equi_msg = (const float*)d_in[2];
    const float* inv_msg  = (const float*)d_in[3];
    const int*   adj      = (const int*)d_in[4];
    const float* W_coord  = (const float*)d_in[5];
    const float* W_eo     = (const float*)d_in[6];
    const float* b_eo     = (const float*)d_in[7];
    const float* W_in     = (const float*)d_in[8];
    const float* b_in     = (const float*)d_in[9];
    const float* W_out    = (const float*)d_in[10];
    const float* b_out    = (const float*)d_in[11];
    float* out = (float*)d_out;

    char* ws = (char*)d_ws;
    u16* proj_equi = (u16*)(ws);                 // 786432 B
    u16* proj_inv  = (u16*)(ws + 786432);        // 1048576 B

    k_prologue<<<dim3(640), dim3(256), 0, stream>>>(
        v_inv, W_in, b_in, proj_inv, v_equi, W_coord, proj_equi);
    k_fused_attn<<<dim3(4096), dim3(256), 0, stream>>>(
        equi_msg, inv_msg, adj, proj_equi, proj_inv,
        W_eo, b_eo, W_out, b_out, out);
}

// Round 4
// 405.154 us; speedup vs baseline: 1.1988x; 1.1988x over previous
//
#include <hip/hip_runtime.h>
#include <hip/hip_bf16.h>
#include <stdint.h>

typedef unsigned short u16;

#define NINF (-__builtin_huge_valf())

__device__ __forceinline__ u16 f2bf(float f) {
    unsigned int u = __float_as_uint(f);
    u += 0x7FFFu + ((u >> 16) & 1u);   // round-to-nearest-even
    return (u16)(u >> 16);
}
__device__ __forceinline__ void unpack8(uint4 u, float* f) {
    f[0] = __uint_as_float(u.x << 16);
    f[1] = __uint_as_float(u.x & 0xFFFF0000u);
    f[2] = __uint_as_float(u.y << 16);
    f[3] = __uint_as_float(u.y & 0xFFFF0000u);
    f[4] = __uint_as_float(u.z << 16);
    f[5] = __uint_as_float(u.z & 0xFFFF0000u);
    f[6] = __uint_as_float(u.w << 16);
    f[7] = __uint_as_float(u.w & 0xFFFF0000u);
}
__device__ __forceinline__ void unpack4(uint2 u, float* f) {
    f[0] = __uint_as_float(u.x << 16);
    f[1] = __uint_as_float(u.x & 0xFFFF0000u);
    f[2] = __uint_as_float(u.y << 16);
    f[3] = __uint_as_float(u.y & 0xFFFF0000u);
}

// ---------------------------------------------------------------------------
// Prologue (fused): blocks [0,256)   -> proj_inv = v_inv @ W_in^T + b_in (bf16)
//                   blocks [256,640) -> proj_equi = v_equi @ W_coord^T  (bf16)
// ---------------------------------------------------------------------------
__global__ __launch_bounds__(256) void k_prologue(
    const float* __restrict__ v_inv,    // [2048, 256]
    const float* __restrict__ W_in,     // [256, 256] (o,i)
    const float* __restrict__ b_in,     // [256]
    u16* __restrict__ proj_inv,         // [2048, 256] bf16
    const float* __restrict__ v_equi,   // [6144, 64] (rows = b*n*3)
    const float* __restrict__ W_coord,  // [64, 64] (o,c)
    u16* __restrict__ proj_equi)        // [6144, 64] bf16
{
    int t = threadIdx.x;
    __shared__ float Xs[8][256];
    __shared__ float Es[16][64];

    if (blockIdx.x < 256) {
        int r0 = blockIdx.x * 8;
#pragma unroll
        for (int i = 0; i < 8; ++i)
            Xs[i][t] = v_inv[(size_t)(r0 + i) * 256 + t];
        __syncthreads();
        float acc[8];
        float bv = b_in[t];
#pragma unroll
        for (int r = 0; r < 8; ++r) acc[r] = bv;
        const float* wrow = W_in + t * 256;
        for (int i = 0; i < 256; i += 4) {
            float4 w = *(const float4*)(wrow + i);
#pragma unroll
            for (int r = 0; r < 8; ++r) {
                acc[r] += Xs[r][i + 0] * w.x;
                acc[r] += Xs[r][i + 1] * w.y;
                acc[r] += Xs[r][i + 2] * w.z;
                acc[r] += Xs[r][i + 3] * w.w;
            }
        }
#pragma unroll
        for (int r = 0; r < 8; ++r)
            proj_inv[(size_t)(r0 + r) * 256 + t] = f2bf(acc[r]);
    } else {
        int bi = blockIdx.x - 256;            // [0,384), 16 rows each
        const float* src = v_equi + (size_t)bi * 1024;
        ((float4*)Es)[t] = *(const float4*)(src + t * 4);
        __syncthreads();
        int o = t & 63, rr = t >> 6;
        float acc[4] = {0.f, 0.f, 0.f, 0.f};
        const float* wrow = W_coord + o * 64;
#pragma unroll
        for (int c = 0; c < 64; c += 4) {
            float4 w = *(const float4*)(wrow + c);
#pragma unroll
            for (int m = 0; m < 4; ++m) {
                int r = rr + 4 * m;
                acc[m] += Es[r][c + 0] * w.x + Es[r][c + 1] * w.y
                        + Es[r][c + 2] * w.z + Es[r][c + 3] * w.w;
            }
        }
        u16* dst = proj_equi + (size_t)bi * 1024;
#pragma unroll
        for (int m = 0; m < 4; ++m)
            dst[(rr + 4 * m) * 64 + o] = f2bf(acc[m]);
    }
}

// ---------------------------------------------------------------------------
// Fused attention kernel.
//   blocks [0,2048)    : equi attention, one (b,q) per block
//                        (kk-reduction via __shfl_xor butterfly: LDS 25KB->5KB)
//   blocks [2048,4096) : inv attention, one (b,q) per block + fused W_out GEMV
// Union LDS = 22160 B -> 7 blocks/CU (28/32 waves), LDS-limited.
// NOTE: no min-waves in __launch_bounds__ — round 3 showed (256,7) makes the
// backend crush VGPRs to 36 and spill ~450 MB to scratch (WRITE_SIZE blowup).
// Natural allocation (~48-80 VGPR) supports 8 waves/SIMD; LDS is the limiter.
// ---------------------------------------------------------------------------
struct SmemEqui {
    float maskv[256];
    int   anyflag;
    int   pad[3];
    float wp[4][5][64];     // per-wave partials: s, s2, a0, a1, a2
    float out_s[3][64];
};
struct SmemInv {
    float maskv[256];
    int   anyflag;
    int   pad[3];
    float p_s[256][16];
    float sh_sp[4][16];
    float sh_s2p[4][16];
    float sh_s[16];
    float sh_s2[16];
    float red[4][256];      // red[0] is reused for the scaled out_i vector
};
union SmemU {
    SmemEqui e;
    SmemInv  i;
};

__global__ __launch_bounds__(256) void k_fused_attn(
    const float* __restrict__ equi_msg,  // [B,256,256,64] fp32
    const float* __restrict__ inv_msg,   // [B,256,256,16] fp32
    const int* __restrict__ adj,         // [B,256,256]
    const u16* __restrict__ proj_equi,   // [B,256,3,64] bf16 (ws)
    const u16* __restrict__ proj_inv,    // [B,256,256] bf16 (ws)
    const float* __restrict__ W_eo,      // [64,64] (o,c)
    const float* __restrict__ b_eo,      // [64]
    const float* __restrict__ W_out,     // [256,256] (o,i)
    const float* __restrict__ b_out,     // [256]
    float* __restrict__ out)             // equi: [B,256,3,64] then inv: [B,256,256]
{
    __shared__ SmemU S;
    int t = threadIdx.x;

    if (blockIdx.x < 2048) {
        // ================= equi path =================
        int bq = blockIdx.x;
        int b = bq >> 8;

        if (t == 0) S.e.anyflag = 0;
        __syncthreads();
        int a = adj[(size_t)bq * 256 + t];
        if (a != 0) S.e.anyflag = 1;
        __syncthreads();
        S.e.maskv[t] = (a == 0 && S.e.anyflag != 0) ? NINF : 0.0f;
        __syncthreads();

        int kk = t >> 3;            // [0,32): k-group; within a wave = lane bits 3..5
        int c0 = (t & 7) * 8;       // channel group start
        float s[8], s2[8], a0[8], a1[8], a2[8];
#pragma unroll
        for (int u = 0; u < 8; ++u) { s[u] = 0.f; s2[u] = 0.f; a0[u] = 0.f; a1[u] = 0.f; a2[u] = 0.f; }

        const float* msg_base = equi_msg + (size_t)bq * 16384;
        const u16* proj_base = proj_equi + (size_t)b * 49152;
        const float* mrow = msg_base + kk * 64 + c0;    // stride per j: 32 rows * 64 = 2048 floats

        // 1-deep software prefetch on the long-latency msg stream
        float4 cur0 = *(const float4*)(mrow);
        float4 cur1 = *(const float4*)(mrow + 4);
#pragma unroll
        for (int j = 0; j < 8; ++j) {
            float4 nx0 = cur0, nx1 = cur1;
            if (j < 7) {
                nx0 = *(const float4*)(mrow + (j + 1) * 2048);
                nx1 = *(const float4*)(mrow + (j + 1) * 2048 + 4);
            }
            int k = kk + 32 * j;
            float m = S.e.maskv[k];
            const u16* pb = proj_base + k * 192 + c0;
            uint4 up0 = *(const uint4*)(pb);
            uint4 up1 = *(const uint4*)(pb + 64);
            uint4 up2 = *(const uint4*)(pb + 128);
            float mv[8], p0[8], p1[8], p2[8];
            mv[0] = cur0.x; mv[1] = cur0.y; mv[2] = cur0.z; mv[3] = cur0.w;
            mv[4] = cur1.x; mv[5] = cur1.y; mv[6] = cur1.z; mv[7] = cur1.w;
            unpack8(up0, p0); unpack8(up1, p1); unpack8(up2, p2);
#pragma unroll
            for (int u = 0; u < 8; ++u) {
                float e = __expf(mv[u] + m);
                s[u] += e;
                s2[u] += e * e;
                a0[u] += e * p0[u];
                a1[u] += e * p1[u];
                a2[u] += e * p2[u];
            }
            cur0 = nx0; cur1 = nx1;
        }

        // ---- reduce over kk: butterfly across lane bits 3..5 (8 kk per wave)
#pragma unroll
        for (int msk = 8; msk <= 32; msk <<= 1) {
#pragma unroll
            for (int u = 0; u < 8; ++u) {
                s[u]  += __shfl_xor(s[u],  msk);
                s2[u] += __shfl_xor(s2[u], msk);
                a0[u] += __shfl_xor(a0[u], msk);
                a1[u] += __shfl_xor(a1[u], msk);
                a2[u] += __shfl_xor(a2[u], msk);
            }
        }
        {
            int w = t >> 6;
            if ((t & 63) < 8) {     // lane l<8 holds wave-sum for c = l*8..l*8+7
#pragma unroll
                for (int u = 0; u < 8; ++u) {
                    S.e.wp[w][0][c0 + u] = s[u];
                    S.e.wp[w][1][c0 + u] = s2[u];
                    S.e.wp[w][2][c0 + u] = a0[u];
                    S.e.wp[w][3][c0 + u] = a1[u];
                    S.e.wp[w][4][c0 + u] = a2[u];
                }
            }
        }
        __syncthreads();
        if (t < 192) {
            int d = t >> 6, c = t & 63;
            float ssum = 0.f, s2sum = 0.f, asum = 0.f;
#pragma unroll
            for (int w = 0; w < 4; ++w) {
                ssum  += S.e.wp[w][0][c];
                s2sum += S.e.wp[w][1][c];
                asum  += S.e.wp[w][2 + d][c];
            }
            float scale = sqrtf(s2sum) / (ssum * ssum);
            S.e.out_s[d][c] = asum * scale;
        }
        __syncthreads();
        if (t < 192) {
            int d = t >> 6, o = t & 63;
            float acc = b_eo[o];
            const float* wr = W_eo + o * 64;
#pragma unroll
            for (int c4 = 0; c4 < 64; c4 += 4) {
                float4 w = *(const float4*)(wr + c4);
                acc += S.e.out_s[d][c4 + 0] * w.x;
                acc += S.e.out_s[d][c4 + 1] * w.y;
                acc += S.e.out_s[d][c4 + 2] * w.z;
                acc += S.e.out_s[d][c4 + 3] * w.w;
            }
            out[(size_t)bq * 192 + t] = acc;
        }
    } else {
        // ================= inv path: one (b,q) per block =================
        int bq = blockIdx.x - 2048;
        int b = bq >> 8;

        if (t == 0) S.i.anyflag = 0;
        __syncthreads();
        int a = adj[(size_t)bq * 256 + t];
        if (a != 0) S.i.anyflag = 1;
        __syncthreads();
        S.i.maskv[t] = (a == 0 && S.i.anyflag != 0) ? NINF : 0.0f;
        __syncthreads();

        // ---- pass 1: exps (float4 over 4 heads) + s/s2 via shuffle butterfly
        {
            int hq = t & 3;            // head quad: h = hq*4 .. hq*4+3
            int kkg = t >> 2;          // [0,64)
            const float* mb = inv_msg + (size_t)bq * 4096;
            float ss[4] = {0.f, 0.f, 0.f, 0.f};
            float ss2[4] = {0.f, 0.f, 0.f, 0.f};
#pragma unroll
            for (int j = 0; j < 4; ++j) {
                int k = kkg + 64 * j;
                float4 v = *(const float4*)(mb + k * 16 + hq * 4);
                float mval = S.i.maskv[k];
                float e0 = __expf(v.x + mval);
                float e1 = __expf(v.y + mval);
                float e2 = __expf(v.z + mval);
                float e3 = __expf(v.w + mval);
                *(float4*)(&S.i.p_s[k][hq * 4]) = make_float4(e0, e1, e2, e3);
                ss[0] += e0; ss[1] += e1; ss[2] += e2; ss[3] += e3;
                ss2[0] += e0 * e0; ss2[1] += e1 * e1;
                ss2[2] += e2 * e2; ss2[3] += e3 * e3;
            }
            // lane = (kkg&15)*4 + hq; reduce over the 16 k-groups of this wave
#pragma unroll
            for (int m = 4; m <= 32; m <<= 1) {
#pragma unroll
                for (int i = 0; i < 4; ++i) {
                    ss[i]  += __shfl_xor(ss[i], m);
                    ss2[i] += __shfl_xor(ss2[i], m);
                }
            }
            if ((t & 63) < 4) {
                int w = t >> 6;
                *(float4*)(&S.i.sh_sp[w][hq * 4])  = make_float4(ss[0], ss[1], ss[2], ss[3]);
                *(float4*)(&S.i.sh_s2p[w][hq * 4]) = make_float4(ss2[0], ss2[1], ss2[2], ss2[3]);
            }
        }
        __syncthreads();
        if (t < 32) {
            int sel = t >> 4, h = t & 15;
            if (sel == 0)
                S.i.sh_s[h] = S.i.sh_sp[0][h] + S.i.sh_sp[1][h]
                            + S.i.sh_sp[2][h] + S.i.sh_sp[3][h];
            else
                S.i.sh_s2[h] = S.i.sh_s2p[0][h] + S.i.sh_s2p[1][h]
                             + S.i.sh_s2p[2][h] + S.i.sh_s2p[3][h];
        }
        __syncthreads();

        // ---- pass 2: out_i[h,e] = sum_k p[k,h] * proj[b,k,h*16+e]
        {
            int kk2 = t >> 6, h = (t >> 2) & 15, eg = t & 3;
            float acc[4] = {0.f, 0.f, 0.f, 0.f};
            const u16* pb = proj_inv + (size_t)b * 65536 + h * 16 + eg * 4;
#pragma unroll 8
            for (int j = 0; j < 64; ++j) {
                int k = kk2 + 4 * j;
                uint2 u = *(const uint2*)(pb + (size_t)k * 256);
                float w[4]; unpack4(u, w);
                float p = S.i.p_s[k][h];
#pragma unroll
                for (int ii = 0; ii < 4; ++ii) acc[ii] += p * w[ii];
            }
#pragma unroll
            for (int ii = 0; ii < 4; ++ii)
                S.i.red[kk2][h * 16 + eg * 4 + ii] = acc[ii];
        }
        __syncthreads();
        {
            // thread t only reads column t, then overwrites red[0][t]: no race
            int h = t >> 4;
            float sum = S.i.red[0][t] + S.i.red[1][t] + S.i.red[2][t] + S.i.red[3][t];
            float sv = S.i.sh_s[h];
            S.i.red[0][t] = sum * sqrtf(S.i.sh_s2[h]) / (sv * sv);
        }
        __syncthreads();

        // ---- fused epilogue: inv_updates[bq,o] = b_out[o] + out_i . W_out[o,:]
        {
            float acc = b_out[t];
            const float* wrow = W_out + t * 256;
#pragma unroll 8
            for (int i = 0; i < 256; i += 4) {
                float4 w = *(const float4*)(wrow + i);
                acc += S.i.red[0][i + 0] * w.x;
                acc += S.i.red[0][i + 1] * w.y;
                acc += S.i.red[0][i + 2] * w.z;
                acc += S.i.red[0][i + 3] * w.w;
            }
            out[393216 + (size_t)bq * 256 + t] = acc;
        }
    }
}

// ---------------------------------------------------------------------------
extern "C" void kernel_launch(void* const* d_in, const int* in_sizes, int n_in,
                              void* d_out, int out_size, void* d_ws, size_t ws_size,
                              hipStream_t stream) {
    (void)in_sizes; (void)n_in; (void)out_size; (void)ws_size;

    const float* v_equi   = (const float*)d_in[0];
    const float* v_inv    = (const float*)d_in[1];
    const float* equi_msg = (const float*)d_in[2];
    const float* inv_msg  = (const float*)d_in[3];
    const int*   adj      = (const int*)d_in[4];
    const float* W_coord  = (const float*)d_in[5];
    const float* W_eo     = (const float*)d_in[6];
    const float* b_eo     = (const float*)d_in[7];
    const float* W_in     = (const float*)d_in[8];
    const float* b_in     = (const float*)d_in[9];
    const float* W_out    = (const float*)d_in[10];
    const float* b_out    = (const float*)d_in[11];
    float* out = (float*)d_out;

    char* ws = (char*)d_ws;
    u16* proj_equi = (u16*)(ws);                 // 786432 B
    u16* proj_inv  = (u16*)(ws + 786432);        // 1048576 B

    k_prologue<<<dim3(640), dim3(256), 0, stream>>>(
        v_inv, W_in, b_in, proj_inv, v_equi, W_coord, proj_equi);
    k_fused_attn<<<dim3(4096), dim3(256), 0, stream>>>(
        equi_msg, inv_msg, adj, proj_equi, proj_inv,
        W_eo, b_eo, W_out, b_out, out);
}

// Round 5
// 319.968 us; speedup vs baseline: 1.5180x; 1.2662x over previous
//
#include <hip/hip_runtime.h>
#include <hip/hip_bf16.h>
#include <stdint.h>

typedef unsigned short u16;

#define NINF (-__builtin_huge_valf())

__device__ __forceinline__ u16 f2bf(float f) {
    unsigned int u = __float_as_uint(f);
    u += 0x7FFFu + ((u >> 16) & 1u);   // round-to-nearest-even
    return (u16)(u >> 16);
}
__device__ __forceinline__ void unpack4(uint2 u, float* f) {
    f[0] = __uint_as_float(u.x << 16);
    f[1] = __uint_as_float(u.x & 0xFFFF0000u);
    f[2] = __uint_as_float(u.y << 16);
    f[3] = __uint_as_float(u.y & 0xFFFF0000u);
}

// ---------------------------------------------------------------------------
// Prologue (fused): blocks [0,256)   -> proj_inv = v_inv @ W_in^T + b_in (bf16)
//                   blocks [256,640) -> proj_equi = v_equi @ W_coord^T  (bf16)
// ---------------------------------------------------------------------------
__global__ __launch_bounds__(256) void k_prologue(
    const float* __restrict__ v_inv,    // [2048, 256]
    const float* __restrict__ W_in,     // [256, 256] (o,i)
    const float* __restrict__ b_in,     // [256]
    u16* __restrict__ proj_inv,         // [2048, 256] bf16
    const float* __restrict__ v_equi,   // [6144, 64] (rows = b*n*3)
    const float* __restrict__ W_coord,  // [64, 64] (o,c)
    u16* __restrict__ proj_equi)        // [6144, 64] bf16
{
    int t = threadIdx.x;
    __shared__ float Xs[8][256];
    __shared__ float Es[16][64];

    if (blockIdx.x < 256) {
        int r0 = blockIdx.x * 8;
#pragma unroll
        for (int i = 0; i < 8; ++i)
            Xs[i][t] = v_inv[(size_t)(r0 + i) * 256 + t];
        __syncthreads();
        float acc[8];
        float bv = b_in[t];
#pragma unroll
        for (int r = 0; r < 8; ++r) acc[r] = bv;
        const float* wrow = W_in + t * 256;
        for (int i = 0; i < 256; i += 4) {
            float4 w = *(const float4*)(wrow + i);
#pragma unroll
            for (int r = 0; r < 8; ++r) {
                acc[r] += Xs[r][i + 0] * w.x;
                acc[r] += Xs[r][i + 1] * w.y;
                acc[r] += Xs[r][i + 2] * w.z;
                acc[r] += Xs[r][i + 3] * w.w;
            }
        }
#pragma unroll
        for (int r = 0; r < 8; ++r)
            proj_inv[(size_t)(r0 + r) * 256 + t] = f2bf(acc[r]);
    } else {
        int bi = blockIdx.x - 256;            // [0,384), 16 rows each
        const float* src = v_equi + (size_t)bi * 1024;
        ((float4*)Es)[t] = *(const float4*)(src + t * 4);
        __syncthreads();
        int o = t & 63, rr = t >> 6;
        float acc[4] = {0.f, 0.f, 0.f, 0.f};
        const float* wrow = W_coord + o * 64;
#pragma unroll
        for (int c = 0; c < 64; c += 4) {
            float4 w = *(const float4*)(wrow + c);
#pragma unroll
            for (int m = 0; m < 4; ++m) {
                int r = rr + 4 * m;
                acc[m] += Es[r][c + 0] * w.x + Es[r][c + 1] * w.y
                        + Es[r][c + 2] * w.z + Es[r][c + 3] * w.w;
            }
        }
        u16* dst = proj_equi + (size_t)bi * 1024;
#pragma unroll
        for (int m = 0; m < 4; ++m)
            dst[(rr + 4 * m) * 64 + o] = f2bf(acc[m]);
    }
}

// ---------------------------------------------------------------------------
// Fused attention kernel.
//   blocks [0,2048)    : equi attention, one (b,q) per block
//                        thread = (k-group kk = t>>4, channel quad c0 = (t&15)*4)
//                        -> only 20 accumulator VGPRs (5 quantities x 4 channels)
//   blocks [2048,4096) : inv attention, one (b,q) per block + fused W_out GEMV
// Union LDS = 22160 B -> 7 blocks/CU (28/32 waves), LDS-limited.
// VGPR history: (256,7) forced 36 -> 450MB spill (round 3). Natural alloc with
// manual prefetch + full unroll -> 136 VGPR -> 8 waves/CU cliff (round 4).
// This version: small accumulator state + '#pragma unroll 2' so the NATURAL
// allocation lands <=64 VGPR (the 8-waves/SIMD boundary). No min-waves bound.
// ---------------------------------------------------------------------------
struct SmemEqui {
    float maskv[256];
    int   anyflag;
    int   pad[3];
    float wp[4][5][64];     // per-wave partials: s, s2, a0, a1, a2
    float out_s[3][64];
};
struct SmemInv {
    float maskv[256];
    int   anyflag;
    int   pad[3];
    float p_s[256][16];
    float sh_sp[4][16];
    float sh_s2p[4][16];
    float sh_s[16];
    float sh_s2[16];
    float red[4][256];      // red[0] is reused for the scaled out_i vector
};
union SmemU {
    SmemEqui e;
    SmemInv  i;
};

__global__ __launch_bounds__(256) void k_fused_attn(
    const float* __restrict__ equi_msg,  // [B,256,256,64] fp32
    const float* __restrict__ inv_msg,   // [B,256,256,16] fp32
    const int* __restrict__ adj,         // [B,256,256]
    const u16* __restrict__ proj_equi,   // [B,256,3,64] bf16 (ws)
    const u16* __restrict__ proj_inv,    // [B,256,256] bf16 (ws)
    const float* __restrict__ W_eo,      // [64,64] (o,c)
    const float* __restrict__ b_eo,      // [64]
    const float* __restrict__ W_out,     // [256,256] (o,i)
    const float* __restrict__ b_out,     // [256]
    float* __restrict__ out)             // equi: [B,256,3,64] then inv: [B,256,256]
{
    __shared__ SmemU S;
    int t = threadIdx.x;

    if (blockIdx.x < 2048) {
        // ================= equi path =================
        int bq = blockIdx.x;
        int b = bq >> 8;

        if (t == 0) S.e.anyflag = 0;
        __syncthreads();
        int a = adj[(size_t)bq * 256 + t];
        if (a != 0) S.e.anyflag = 1;
        __syncthreads();
        S.e.maskv[t] = (a == 0 && S.e.anyflag != 0) ? NINF : 0.0f;
        __syncthreads();

        int kk = t >> 4;            // [0,16): k-group; in-wave = lane bits 4..5
        int c0 = (t & 15) * 4;      // channel quad start
        float s[4], s2[4], a0[4], a1[4], a2[4];
#pragma unroll
        for (int u = 0; u < 4; ++u) { s[u] = 0.f; s2[u] = 0.f; a0[u] = 0.f; a1[u] = 0.f; a2[u] = 0.f; }

        const float* msg_base = equi_msg + (size_t)bq * 16384;
        const u16* proj_base = proj_equi + (size_t)b * 49152;

#pragma unroll 2
        for (int j = 0; j < 16; ++j) {
            int k = kk + 16 * j;
            float m = S.e.maskv[k];
            float4 mv4 = *(const float4*)(msg_base + k * 64 + c0);
            const u16* pb = proj_base + k * 192 + c0;
            uint2 q0 = *(const uint2*)(pb);
            uint2 q1 = *(const uint2*)(pb + 64);
            uint2 q2 = *(const uint2*)(pb + 128);
            float mv[4], p0[4], p1[4], p2[4];
            mv[0] = mv4.x; mv[1] = mv4.y; mv[2] = mv4.z; mv[3] = mv4.w;
            unpack4(q0, p0); unpack4(q1, p1); unpack4(q2, p2);
#pragma unroll
            for (int u = 0; u < 4; ++u) {
                float e = __expf(mv[u] + m);
                s[u] += e;
                s2[u] += e * e;
                a0[u] += e * p0[u];
                a1[u] += e * p1[u];
                a2[u] += e * p2[u];
            }
        }

        // ---- reduce over kk within wave: butterfly across lane bits 4..5
#pragma unroll
        for (int msk = 16; msk <= 32; msk <<= 1) {
#pragma unroll
            for (int u = 0; u < 4; ++u) {
                s[u]  += __shfl_xor(s[u],  msk);
                s2[u] += __shfl_xor(s2[u], msk);
                a0[u] += __shfl_xor(a0[u], msk);
                a1[u] += __shfl_xor(a1[u], msk);
                a2[u] += __shfl_xor(a2[u], msk);
            }
        }
        {
            int w = t >> 6;
            if ((t & 63) < 16) {    // lane l<16 holds wave-sum for c = l*4..l*4+3
#pragma unroll
                for (int u = 0; u < 4; ++u) {
                    S.e.wp[w][0][c0 + u] = s[u];
                    S.e.wp[w][1][c0 + u] = s2[u];
                    S.e.wp[w][2][c0 + u] = a0[u];
                    S.e.wp[w][3][c0 + u] = a1[u];
                    S.e.wp[w][4][c0 + u] = a2[u];
                }
            }
        }
        __syncthreads();
        if (t < 192) {
            int d = t >> 6, c = t & 63;
            float ssum = 0.f, s2sum = 0.f, asum = 0.f;
#pragma unroll
            for (int w = 0; w < 4; ++w) {
                ssum  += S.e.wp[w][0][c];
                s2sum += S.e.wp[w][1][c];
                asum  += S.e.wp[w][2 + d][c];
            }
            float scale = sqrtf(s2sum) / (ssum * ssum);
            S.e.out_s[d][c] = asum * scale;
        }
        __syncthreads();
        if (t < 192) {
            int d = t >> 6, o = t & 63;
            float acc = b_eo[o];
            const float* wr = W_eo + o * 64;
#pragma unroll
            for (int c4 = 0; c4 < 64; c4 += 4) {
                float4 w = *(const float4*)(wr + c4);
                acc += S.e.out_s[d][c4 + 0] * w.x;
                acc += S.e.out_s[d][c4 + 1] * w.y;
                acc += S.e.out_s[d][c4 + 2] * w.z;
                acc += S.e.out_s[d][c4 + 3] * w.w;
            }
            out[(size_t)bq * 192 + t] = acc;
        }
    } else {
        // ================= inv path: one (b,q) per block =================
        int bq = blockIdx.x - 2048;
        int b = bq >> 8;

        if (t == 0) S.i.anyflag = 0;
        __syncthreads();
        int a = adj[(size_t)bq * 256 + t];
        if (a != 0) S.i.anyflag = 1;
        __syncthreads();
        S.i.maskv[t] = (a == 0 && S.i.anyflag != 0) ? NINF : 0.0f;
        __syncthreads();

        // ---- pass 1: exps (float4 over 4 heads) + s/s2 via shuffle butterfly
        {
            int hq = t & 3;            // head quad: h = hq*4 .. hq*4+3
            int kkg = t >> 2;          // [0,64)
            const float* mb = inv_msg + (size_t)bq * 4096;
            float ss[4] = {0.f, 0.f, 0.f, 0.f};
            float ss2[4] = {0.f, 0.f, 0.f, 0.f};
#pragma unroll
            for (int j = 0; j < 4; ++j) {
                int k = kkg + 64 * j;
                float4 v = *(const float4*)(mb + k * 16 + hq * 4);
                float mval = S.i.maskv[k];
                float e0 = __expf(v.x + mval);
                float e1 = __expf(v.y + mval);
                float e2 = __expf(v.z + mval);
                float e3 = __expf(v.w + mval);
                *(float4*)(&S.i.p_s[k][hq * 4]) = make_float4(e0, e1, e2, e3);
                ss[0] += e0; ss[1] += e1; ss[2] += e2; ss[3] += e3;
                ss2[0] += e0 * e0; ss2[1] += e1 * e1;
                ss2[2] += e2 * e2; ss2[3] += e3 * e3;
            }
            // lane = (kkg&15)*4 + hq; reduce over the 16 k-groups of this wave
#pragma unroll
            for (int m = 4; m <= 32; m <<= 1) {
#pragma unroll
                for (int i = 0; i < 4; ++i) {
                    ss[i]  += __shfl_xor(ss[i], m);
                    ss2[i] += __shfl_xor(ss2[i], m);
                }
            }
            if ((t & 63) < 4) {
                int w = t >> 6;
                *(float4*)(&S.i.sh_sp[w][hq * 4])  = make_float4(ss[0], ss[1], ss[2], ss[3]);
                *(float4*)(&S.i.sh_s2p[w][hq * 4]) = make_float4(ss2[0], ss2[1], ss2[2], ss2[3]);
            }
        }
        __syncthreads();
        if (t < 32) {
            int sel = t >> 4, h = t & 15;
            if (sel == 0)
                S.i.sh_s[h] = S.i.sh_sp[0][h] + S.i.sh_sp[1][h]
                            + S.i.sh_sp[2][h] + S.i.sh_sp[3][h];
            else
                S.i.sh_s2[h] = S.i.sh_s2p[0][h] + S.i.sh_s2p[1][h]
                             + S.i.sh_s2p[2][h] + S.i.sh_s2p[3][h];
        }
        __syncthreads();

        // ---- pass 2: out_i[h,e] = sum_k p[k,h] * proj[b,k,h*16+e]
        {
            int kk2 = t >> 6, h = (t >> 2) & 15, eg = t & 3;
            float acc[4] = {0.f, 0.f, 0.f, 0.f};
            const u16* pb = proj_inv + (size_t)b * 65536 + h * 16 + eg * 4;
#pragma unroll 8
            for (int j = 0; j < 64; ++j) {
                int k = kk2 + 4 * j;
                uint2 u = *(const uint2*)(pb + (size_t)k * 256);
                float w[4]; unpack4(u, w);
                float p = S.i.p_s[k][h];
#pragma unroll
                for (int ii = 0; ii < 4; ++ii) acc[ii] += p * w[ii];
            }
#pragma unroll
            for (int ii = 0; ii < 4; ++ii)
                S.i.red[kk2][h * 16 + eg * 4 + ii] = acc[ii];
        }
        __syncthreads();
        {
            // thread t only reads column t, then overwrites red[0][t]: no race
            int h = t >> 4;
            float sum = S.i.red[0][t] + S.i.red[1][t] + S.i.red[2][t] + S.i.red[3][t];
            float sv = S.i.sh_s[h];
            S.i.red[0][t] = sum * sqrtf(S.i.sh_s2[h]) / (sv * sv);
        }
        __syncthreads();

        // ---- fused epilogue: inv_updates[bq,o] = b_out[o] + out_i . W_out[o,:]
        {
            float acc = b_out[t];
            const float* wrow = W_out + t * 256;
#pragma unroll 8
            for (int i = 0; i < 256; i += 4) {
                float4 w = *(const float4*)(wrow + i);
                acc += S.i.red[0][i + 0] * w.x;
                acc += S.i.red[0][i + 1] * w.y;
                acc += S.i.red[0][i + 2] * w.z;
                acc += S.i.red[0][i + 3] * w.w;
            }
            out[393216 + (size_t)bq * 256 + t] = acc;
        }
    }
}

// ---------------------------------------------------------------------------
extern "C" void kernel_launch(void* const* d_in, const int* in_sizes, int n_in,
                              void* d_out, int out_size, void* d_ws, size_t ws_size,
                              hipStream_t stream) {
    (void)in_sizes; (void)n_in; (void)out_size; (void)ws_size;

    const float* v_equi   = (const float*)d_in[0];
    const float* v_inv    = (const float*)d_in[1];
    const float* equi_msg = (const float*)d_in[2];
    const float* inv_msg  = (const float*)d_in[3];
    const int*   adj      = (const int*)d_in[4];
    const float* W_coord  = (const float*)d_in[5];
    const float* W_eo     = (const float*)d_in[6];
    const float* b_eo     = (const float*)d_in[7];
    const float* W_in     = (const float*)d_in[8];
    const float* b_in     = (const float*)d_in[9];
    const float* W_out    = (const float*)d_in[10];
    const float* b_out    = (const float*)d_in[11];
    float* out = (float*)d_out;

    char* ws = (char*)d_ws;
    u16* proj_equi = (u16*)(ws);                 // 786432 B
    u16* proj_inv  = (u16*)(ws + 786432);        // 1048576 B

    k_prologue<<<dim3(640), dim3(256), 0, stream>>>(
        v_inv, W_in, b_in, proj_inv, v_equi, W_coord, proj_equi);
    k_fused_attn<<<dim3(4096), dim3(256), 0, stream>>>(
        equi_msg, inv_msg, adj, proj_equi, proj_inv,
        W_eo, b_eo, W_out, b_out, out);
}

// Round 6
// 289.373 us; speedup vs baseline: 1.6785x; 1.1057x over previous
//
#include <hip/hip_runtime.h>
#include <hip/hip_bf16.h>
#include <stdint.h>

typedef unsigned short u16;

#define NINF (-__builtin_huge_valf())

__device__ __forceinline__ u16 f2bf(float f) {
    unsigned int u = __float_as_uint(f);
    u += 0x7FFFu + ((u >> 16) & 1u);   // round-to-nearest-even
    return (u16)(u >> 16);
}
__device__ __forceinline__ void unpack4(uint2 u, float* f) {
    f[0] = __uint_as_float(u.x << 16);
    f[1] = __uint_as_float(u.x & 0xFFFF0000u);
    f[2] = __uint_as_float(u.y << 16);
    f[3] = __uint_as_float(u.y & 0xFFFF0000u);
}

// ---------------------------------------------------------------------------
// k_setup: blocks [0,16)   -> WT_out = W_out^T (16 tiles of 64x64)
//          blocks [16,32)  -> WT_in  = W_in^T
//          blocks [32,416) -> proj_equi = v_equi @ W_coord^T (bf16), 16 rows ea
// Transposed weights let every downstream GEMV read W^T[i*256+t]: lane-
// consecutive addresses (4 cacheline-requests/inst) instead of the
// thread-per-row scatter (64 lines/inst).
// ---------------------------------------------------------------------------
__global__ __launch_bounds__(256) void k_setup(
    const float* __restrict__ W_out,   // [256,256] (o,i)
    float* __restrict__ WT_out,        // [256,256] (i,o)  ws
    const float* __restrict__ W_in,    // [256,256] (o,i)
    float* __restrict__ WT_in,         // [256,256] (i,o)  ws
    const float* __restrict__ v_equi,  // [6144, 64]
    const float* __restrict__ W_coord, // [64, 64] (o,c)
    u16* __restrict__ proj_equi)       // [6144, 64] bf16  ws
{
    int t = threadIdx.x;
    if (blockIdx.x < 32) {
        const float* Wsrc = (blockIdx.x < 16) ? W_out : W_in;
        float*       Wdst = (blockIdx.x < 16) ? WT_out : WT_in;
        int tile = blockIdx.x & 15;
        int ti = tile >> 2, tj = tile & 3;     // 4x4 grid of 64x64 tiles
        __shared__ float tl[64][65];
        int r = t >> 2, c4 = (t & 3) * 16;
#pragma unroll
        for (int k = 0; k < 16; k += 4) {
            float4 v = *(const float4*)(Wsrc + (size_t)(ti * 64 + r) * 256 + tj * 64 + c4 + k);
            tl[r][c4 + k + 0] = v.x; tl[r][c4 + k + 1] = v.y;
            tl[r][c4 + k + 2] = v.z; tl[r][c4 + k + 3] = v.w;
        }
        __syncthreads();
        // WT[tj*64 + r][ti*64 + c] = W[ti*64 + c][tj*64 + r] = tl[c][r]
#pragma unroll
        for (int k = 0; k < 16; k += 4) {
            float4 v;
            v.x = tl[c4 + k + 0][r]; v.y = tl[c4 + k + 1][r];
            v.z = tl[c4 + k + 2][r]; v.w = tl[c4 + k + 3][r];
            *(float4*)(Wdst + (size_t)(tj * 64 + r) * 256 + ti * 64 + c4 + k) = v;
        }
    } else {
        int bi = blockIdx.x - 32;             // [0,384), 16 rows each
        __shared__ float Es[16][64];
        const float* src = v_equi + (size_t)bi * 1024;
        ((float4*)Es)[t] = *(const float4*)(src + t * 4);
        __syncthreads();
        int o = t & 63, rr = t >> 6;
        float acc[4] = {0.f, 0.f, 0.f, 0.f};
        const float* wrow = W_coord + o * 64;
#pragma unroll
        for (int c = 0; c < 64; c += 4) {
            float4 w = *(const float4*)(wrow + c);
#pragma unroll
            for (int m = 0; m < 4; ++m) {
                int r = rr + 4 * m;
                acc[m] += Es[r][c + 0] * w.x + Es[r][c + 1] * w.y
                        + Es[r][c + 2] * w.z + Es[r][c + 3] * w.w;
            }
        }
        u16* dst = proj_equi + (size_t)bi * 1024;
#pragma unroll
        for (int m = 0; m < 4; ++m)
            dst[(rr + 4 * m) * 64 + o] = f2bf(acc[m]);
    }
}

// ---------------------------------------------------------------------------
// k_equi_proj: blocks [0,2048)    -> equi attention, one (b,q) per block
//                                    (4-ch layout, VGPR~40, LDS 6.4KB)
//              blocks [2048,2304) -> proj_inv = v_inv @ W_in^T + b_in (bf16),
//                                    8 rows/block, coalesced WT_in reads
// Union LDS = 8KB -> wave-capped 8 blocks/CU (~100% occupancy).
// ---------------------------------------------------------------------------
struct SmemEqui {
    float maskv[256];
    int   anyflag;
    int   pad[3];
    float wp[4][5][64];     // per-wave partials: s, s2, a0, a1, a2
    float out_s[3][64];
};
struct SmemProj {
    float Xs[8][256];
};
union SmemEP {
    SmemEqui e;
    SmemProj p;
};

__global__ __launch_bounds__(256) void k_equi_proj(
    const float* __restrict__ equi_msg,  // [B,256,256,64] fp32
    const int* __restrict__ adj,         // [B,256,256]
    const u16* __restrict__ proj_equi,   // [B,256,3,64] bf16 (ws)
    const float* __restrict__ W_eo,      // [64,64] (o,c)
    const float* __restrict__ b_eo,      // [64]
    float* __restrict__ out,             // equi out at offset 0
    const float* __restrict__ v_inv,     // [2048, 256]
    const float* __restrict__ WT_in,     // [256,256] (i,o) ws
    const float* __restrict__ b_in,      // [256]
    u16* __restrict__ proj_inv)          // [2048, 256] bf16 ws
{
    __shared__ SmemEP S;
    int t = threadIdx.x;

    if (blockIdx.x < 2048) {
        // ================= equi path (round-5 validated body) =============
        int bq = blockIdx.x;
        int b = bq >> 8;

        if (t == 0) S.e.anyflag = 0;
        __syncthreads();
        int a = adj[(size_t)bq * 256 + t];
        if (a != 0) S.e.anyflag = 1;
        __syncthreads();
        S.e.maskv[t] = (a == 0 && S.e.anyflag != 0) ? NINF : 0.0f;
        __syncthreads();

        int kk = t >> 4;            // [0,16): k-group; in-wave = lane bits 4..5
        int c0 = (t & 15) * 4;      // channel quad start
        float s[4], s2[4], a0[4], a1[4], a2[4];
#pragma unroll
        for (int u = 0; u < 4; ++u) { s[u] = 0.f; s2[u] = 0.f; a0[u] = 0.f; a1[u] = 0.f; a2[u] = 0.f; }

        const float* msg_base = equi_msg + (size_t)bq * 16384;
        const u16* proj_base = proj_equi + (size_t)b * 49152;

#pragma unroll 2
        for (int j = 0; j < 16; ++j) {
            int k = kk + 16 * j;
            float m = S.e.maskv[k];
            float4 mv4 = *(const float4*)(msg_base + k * 64 + c0);
            const u16* pb = proj_base + k * 192 + c0;
            uint2 q0 = *(const uint2*)(pb);
            uint2 q1 = *(const uint2*)(pb + 64);
            uint2 q2 = *(const uint2*)(pb + 128);
            float mv[4], p0[4], p1[4], p2[4];
            mv[0] = mv4.x; mv[1] = mv4.y; mv[2] = mv4.z; mv[3] = mv4.w;
            unpack4(q0, p0); unpack4(q1, p1); unpack4(q2, p2);
#pragma unroll
            for (int u = 0; u < 4; ++u) {
                float e = __expf(mv[u] + m);
                s[u] += e;
                s2[u] += e * e;
                a0[u] += e * p0[u];
                a1[u] += e * p1[u];
                a2[u] += e * p2[u];
            }
        }

        // ---- reduce over kk within wave: butterfly across lane bits 4..5
#pragma unroll
        for (int msk = 16; msk <= 32; msk <<= 1) {
#pragma unroll
            for (int u = 0; u < 4; ++u) {
                s[u]  += __shfl_xor(s[u],  msk);
                s2[u] += __shfl_xor(s2[u], msk);
                a0[u] += __shfl_xor(a0[u], msk);
                a1[u] += __shfl_xor(a1[u], msk);
                a2[u] += __shfl_xor(a2[u], msk);
            }
        }
        {
            int w = t >> 6;
            if ((t & 63) < 16) {    // lane l<16 holds wave-sum for c = l*4..l*4+3
#pragma unroll
                for (int u = 0; u < 4; ++u) {
                    S.e.wp[w][0][c0 + u] = s[u];
                    S.e.wp[w][1][c0 + u] = s2[u];
                    S.e.wp[w][2][c0 + u] = a0[u];
                    S.e.wp[w][3][c0 + u] = a1[u];
                    S.e.wp[w][4][c0 + u] = a2[u];
                }
            }
        }
        __syncthreads();
        if (t < 192) {
            int d = t >> 6, c = t & 63;
            float ssum = 0.f, s2sum = 0.f, asum = 0.f;
#pragma unroll
            for (int w = 0; w < 4; ++w) {
                ssum  += S.e.wp[w][0][c];
                s2sum += S.e.wp[w][1][c];
                asum  += S.e.wp[w][2 + d][c];
            }
            float scale = sqrtf(s2sum) / (ssum * ssum);
            S.e.out_s[d][c] = asum * scale;
        }
        __syncthreads();
        if (t < 192) {
            int d = t >> 6, o = t & 63;
            float acc = b_eo[o];
            const float* wr = W_eo + o * 64;
#pragma unroll
            for (int c4 = 0; c4 < 64; c4 += 4) {
                float4 w = *(const float4*)(wr + c4);
                acc += S.e.out_s[d][c4 + 0] * w.x;
                acc += S.e.out_s[d][c4 + 1] * w.y;
                acc += S.e.out_s[d][c4 + 2] * w.z;
                acc += S.e.out_s[d][c4 + 3] * w.w;
            }
            out[(size_t)bq * 192 + t] = acc;
        }
    } else {
        // ================= proj_inv GEMM: 8 rows/block, coalesced WT_in ====
        int r0 = (blockIdx.x - 2048) * 8;
#pragma unroll
        for (int i = 0; i < 8; ++i)
            S.p.Xs[i][t] = v_inv[(size_t)(r0 + i) * 256 + t];
        __syncthreads();
        float acc[8];
        float bv = b_in[t];
#pragma unroll
        for (int r = 0; r < 8; ++r) acc[r] = bv;
#pragma unroll 8
        for (int i = 0; i < 256; ++i) {
            float w = WT_in[i * 256 + t];     // lane-consecutive: coalesced
#pragma unroll
            for (int r = 0; r < 8; ++r) acc[r] += S.p.Xs[r][i] * w;
        }
#pragma unroll
        for (int r = 0; r < 8; ++r)
            proj_inv[(size_t)(r0 + r) * 256 + t] = f2bf(acc[r]);
    }
}

// ---------------------------------------------------------------------------
// Inv attention, 2 q-rows per block (grid 1024) — round-0 validated body.
// ---------------------------------------------------------------------------
__global__ __launch_bounds__(256) void k_inv_attn2(
    const float* __restrict__ inv_msg,  // [B,256,256,16] fp32
    const int* __restrict__ adj,        // [B,256,256]
    const u16* __restrict__ proj,       // [B,256,256] bf16 (ws)
    float* __restrict__ out_rows)       // [2048,256] fp32 (ws)
{
    int bq2 = blockIdx.x;               // [0,1024), 2 q's each
    int b = bq2 >> 7;
    int t = threadIdx.x;

    __shared__ float maskv[2][256];
    __shared__ int anyflag[2];
    __shared__ float p_s[2][256][16];
    __shared__ float spart[2][16][16], s2part[2][16][16];
    __shared__ float sh_s[2][16], sh_s2[2][16];
    __shared__ float red[4][2][256];

    if (t < 2) anyflag[t] = 0;
    __syncthreads();
    int a0 = adj[((size_t)bq2 * 2 + 0) * 256 + t];
    int a1 = adj[((size_t)bq2 * 2 + 1) * 256 + t];
    if (a0 != 0) anyflag[0] = 1;
    if (a1 != 0) anyflag[1] = 1;
    __syncthreads();
    maskv[0][t] = (a0 == 0 && anyflag[0] != 0) ? NINF : 0.0f;
    maskv[1][t] = (a1 == 0 && anyflag[1] != 0) ? NINF : 0.0f;
    __syncthreads();

    // pass 1: exps + per-head s, s2 partials
    {
        int h = t & 15, kk = t >> 4;
#pragma unroll
        for (int q = 0; q < 2; ++q) {
            const float* mb = inv_msg + ((size_t)bq2 * 2 + q) * 4096;
            float ss = 0.f, ss2 = 0.f;
#pragma unroll
            for (int j = 0; j < 16; ++j) {
                int k = kk + 16 * j;
                float e = __expf(mb[k * 16 + h] + maskv[q][k]);
                p_s[q][k][h] = e;
                ss += e; ss2 += e * e;
            }
            spart[q][kk][h] = ss;
            s2part[q][kk][h] = ss2;
        }
    }
    __syncthreads();
    if (t < 64) {
        int q = t >> 5, sel = (t >> 4) & 1, h = t & 15;
        float sum = 0.f;
        if (sel == 0) {
#pragma unroll
            for (int kk = 0; kk < 16; ++kk) sum += spart[q][kk][h];
            sh_s[q][h] = sum;
        } else {
#pragma unroll
            for (int kk = 0; kk < 16; ++kk) sum += s2part[q][kk][h];
            sh_s2[q][h] = sum;
        }
    }
    __syncthreads();

    // pass 2: out_i[q,h,e] = sum_k p[q,k,h] * proj[b,k,h*16+e]
    {
        int kk2 = t >> 6, h = (t >> 2) & 15, eg = t & 3;
        float acc0[4] = {0.f, 0.f, 0.f, 0.f};
        float acc1[4] = {0.f, 0.f, 0.f, 0.f};
        const u16* pb = proj + (size_t)b * 65536 + h * 16 + eg * 4;
        for (int j = 0; j < 64; ++j) {
            int k = kk2 + 4 * j;
            uint2 u = *(const uint2*)(pb + (size_t)k * 256);
            float w[4]; unpack4(u, w);
            float pq0 = p_s[0][k][h];
            float pq1 = p_s[1][k][h];
#pragma unroll
            for (int ii = 0; ii < 4; ++ii) {
                acc0[ii] += pq0 * w[ii];
                acc1[ii] += pq1 * w[ii];
            }
        }
#pragma unroll
        for (int ii = 0; ii < 4; ++ii) {
            red[kk2][0][h * 16 + eg * 4 + ii] = acc0[ii];
            red[kk2][1][h * 16 + eg * 4 + ii] = acc1[ii];
        }
    }
    __syncthreads();
    {
        int h = t >> 4;
#pragma unroll
        for (int q = 0; q < 2; ++q) {
            float sum = red[0][q][t] + red[1][q][t] + red[2][q][t] + red[3][q][t];
            float sv = sh_s[q][h];
            out_rows[((size_t)bq2 * 2 + q) * 256 + t] = sum * sqrtf(sh_s2[q][h]) / (sv * sv);
        }
    }
}

// ---------------------------------------------------------------------------
// Final epilogue GEMM with transposed weights: Y[r,o] = sum_i X[r,i]*WT[i,o]+b
// ---------------------------------------------------------------------------
__global__ __launch_bounds__(256) void k_rowgemm_tof32(
    const float* __restrict__ X,     // [2048, 256] fp32 (ws)
    const float* __restrict__ WT,    // [256, 256] (i,o) ws
    const float* __restrict__ bias,  // [256]
    float* __restrict__ Y)           // [2048, 256] fp32
{
    int r0 = blockIdx.x * 8;
    int t = threadIdx.x;
    __shared__ float Xs[8][256];
#pragma unroll
    for (int i = 0; i < 8; ++i)
        Xs[i][t] = X[(size_t)(r0 + i) * 256 + t];
    __syncthreads();
    float acc[8];
    float bv = bias[t];
#pragma unroll
    for (int r = 0; r < 8; ++r) acc[r] = bv;
#pragma unroll 8
    for (int i = 0; i < 256; ++i) {
        float w = WT[i * 256 + t];           // lane-consecutive: coalesced
#pragma unroll
        for (int r = 0; r < 8; ++r) acc[r] += Xs[r][i] * w;
    }
#pragma unroll
    for (int r = 0; r < 8; ++r)
        Y[(size_t)(r0 + r) * 256 + t] = acc[r];
}

// ---------------------------------------------------------------------------
extern "C" void kernel_launch(void* const* d_in, const int* in_sizes, int n_in,
                              void* d_out, int out_size, void* d_ws, size_t ws_size,
                              hipStream_t stream) {
    (void)in_sizes; (void)n_in; (void)out_size; (void)ws_size;

    const float* v_equi   = (const float*)d_in[0];
    const float* v_inv    = (const float*)d_in[1];
    const float* equi_msg = (const float*)d_in[2];
    const float* inv_msg  = (const float*)d_in[3];
    const int*   adj      = (const int*)d_in[4];
    const float* W_coord  = (const float*)d_in[5];
    const float* W_eo     = (const float*)d_in[6];
    const float* b_eo     = (const float*)d_in[7];
    const float* W_in     = (const float*)d_in[8];
    const float* b_in     = (const float*)d_in[9];
    const float* W_out    = (const float*)d_in[10];
    const float* b_out    = (const float*)d_in[11];
    float* out = (float*)d_out;

    char* ws = (char*)d_ws;
    u16*   proj_equi = (u16*)(ws);                   // 786432 B
    u16*   proj_inv  = (u16*)(ws + 786432);          // 1048576 B -> ends 1835008
    float* WT_out    = (float*)(ws + 1835008);       // 262144 B  -> ends 2097152
    float* WT_in     = (float*)(ws + 2097152);       // 262144 B  -> ends 2359296
    float* out_rows  = (float*)(ws + 2359296);       // 2097152 B -> ends 4456448

    k_setup<<<dim3(416), dim3(256), 0, stream>>>(
        W_out, WT_out, W_in, WT_in, v_equi, W_coord, proj_equi);
    k_equi_proj<<<dim3(2304), dim3(256), 0, stream>>>(
        equi_msg, adj, proj_equi, W_eo, b_eo, out,
        v_inv, WT_in, b_in, proj_inv);
    k_inv_attn2<<<dim3(1024), dim3(256), 0, stream>>>(
        inv_msg, adj, proj_inv, out_rows);
    k_rowgemm_tof32<<<dim3(256), dim3(256), 0, stream>>>(
        out_rows, WT_out, b_out, out + 393216);
}

// Round 8
// 287.708 us; speedup vs baseline: 1.6882x; 1.0058x over previous
//
#include <hip/hip_runtime.h>
#include <hip/hip_bf16.h>
#include <stdint.h>

typedef unsigned short u16;

#define NINF (-__builtin_huge_valf())

__device__ __forceinline__ u16 f2bf(float f) {
    unsigned int u = __float_as_uint(f);
    u += 0x7FFFu + ((u >> 16) & 1u);   // round-to-nearest-even
    return (u16)(u >> 16);
}
__device__ __forceinline__ void unpack4(uint2 u, float* f) {
    f[0] = __uint_as_float(u.x << 16);
    f[1] = __uint_as_float(u.x & 0xFFFF0000u);
    f[2] = __uint_as_float(u.y << 16);
    f[3] = __uint_as_float(u.y & 0xFFFF0000u);
}

// ---------------------------------------------------------------------------
// k_setup: blocks [0,16)   -> WT_out = W_out^T ; [16,32) -> WT_in = W_in^T
//          blocks [32,416) -> proj_equi = v_equi @ W_coord^T (bf16)
// ---------------------------------------------------------------------------
__global__ __launch_bounds__(256) void k_setup(
    const float* __restrict__ W_out,   // [256,256] (o,i)
    float* __restrict__ WT_out,        // [256,256] (i,o)  ws
    const float* __restrict__ W_in,    // [256,256] (o,i)
    float* __restrict__ WT_in,         // [256,256] (i,o)  ws
    const float* __restrict__ v_equi,  // [6144, 64]
    const float* __restrict__ W_coord, // [64, 64] (o,c)
    u16* __restrict__ proj_equi)       // [6144, 64] bf16  ws
{
    int t = threadIdx.x;
    if (blockIdx.x < 32) {
        const float* Wsrc = (blockIdx.x < 16) ? W_out : W_in;
        float*       Wdst = (blockIdx.x < 16) ? WT_out : WT_in;
        int tile = blockIdx.x & 15;
        int ti = tile >> 2, tj = tile & 3;     // 4x4 grid of 64x64 tiles
        __shared__ float tl[64][65];
        int r = t >> 2, c4 = (t & 3) * 16;
#pragma unroll
        for (int k = 0; k < 16; k += 4) {
            float4 v = *(const float4*)(Wsrc + (size_t)(ti * 64 + r) * 256 + tj * 64 + c4 + k);
            tl[r][c4 + k + 0] = v.x; tl[r][c4 + k + 1] = v.y;
            tl[r][c4 + k + 2] = v.z; tl[r][c4 + k + 3] = v.w;
        }
        __syncthreads();
#pragma unroll
        for (int k = 0; k < 16; k += 4) {
            float4 v;
            v.x = tl[c4 + k + 0][r]; v.y = tl[c4 + k + 1][r];
            v.z = tl[c4 + k + 2][r]; v.w = tl[c4 + k + 3][r];
            *(float4*)(Wdst + (size_t)(tj * 64 + r) * 256 + ti * 64 + c4 + k) = v;
        }
    } else {
        int bi = blockIdx.x - 32;             // [0,384), 16 rows each
        __shared__ float Es[16][64];
        const float* src = v_equi + (size_t)bi * 1024;
        ((float4*)Es)[t] = *(const float4*)(src + t * 4);
        __syncthreads();
        int o = t & 63, rr = t >> 6;
        float acc[4] = {0.f, 0.f, 0.f, 0.f};
        const float* wrow = W_coord + o * 64;
#pragma unroll
        for (int c = 0; c < 64; c += 4) {
            float4 w = *(const float4*)(wrow + c);
#pragma unroll
            for (int m = 0; m < 4; ++m) {
                int r = rr + 4 * m;
                acc[m] += Es[r][c + 0] * w.x + Es[r][c + 1] * w.y
                        + Es[r][c + 2] * w.z + Es[r][c + 3] * w.w;
            }
        }
        u16* dst = proj_equi + (size_t)bi * 1024;
#pragma unroll
        for (int m = 0; m < 4; ++m)
            dst[(rr + 4 * m) * 64 + o] = f2bf(acc[m]);
    }
}

// ---------------------------------------------------------------------------
// k_equi_proj: blocks [0,2048)    -> equi attention, one (b,q) per block.
//   Round-6 verified structure + 4-deep REGISTER software pipeline:
//   4 statically-named slots (A..D), each = 1 chunk's {float4 msg, 3x uint2
//   proj}; outer loop (#pragma unroll 1) consumes slot k and reloads it 4
//   chunks ahead. Ordinary loads -> compiler auto-waitcnt = correct by
//   construction (no hand vmcnt, no raw barriers; round-7 DMA NaN lesson).
//   Accumulation order identical to round 6 (j = 0..15, k = kk + 16*j).
// blocks [2048,2304) -> proj_inv GEMM (coalesced WT_in), unchanged.
// Union LDS = 8KB.
// ---------------------------------------------------------------------------
struct SmemEqui {
    float maskv[256];
    int   anyflag;
    int   pad[3];
    float wp[4][5][64];     // per-wave partials: s, s2, a0, a1, a2
    float out_s[3][64];
};
struct SmemProj {
    float Xs[8][256];
};
union SmemEP {
    SmemEqui e;
    SmemProj p;
};

__global__ __launch_bounds__(256) void k_equi_proj(
    const float* __restrict__ equi_msg,  // [B,256,256,64] fp32
    const int* __restrict__ adj,         // [B,256,256]
    const u16* __restrict__ proj_equi,   // [B,256,3,64] bf16 (ws)
    const float* __restrict__ W_eo,      // [64,64] (o,c)
    const float* __restrict__ b_eo,      // [64]
    float* __restrict__ out,             // equi out at offset 0
    const float* __restrict__ v_inv,     // [2048, 256]
    const float* __restrict__ WT_in,     // [256,256] (i,o) ws
    const float* __restrict__ b_in,      // [256]
    u16* __restrict__ proj_inv)          // [2048, 256] bf16 ws
{
    __shared__ SmemEP S;
    int t = threadIdx.x;

    if (blockIdx.x < 2048) {
        // ================= equi path, reg-pipelined =================
        int bq = blockIdx.x;
        int b = bq >> 8;

        if (t == 0) S.e.anyflag = 0;
        __syncthreads();
        int a = adj[(size_t)bq * 256 + t];
        if (a != 0) S.e.anyflag = 1;
        __syncthreads();
        S.e.maskv[t] = (a == 0 && S.e.anyflag != 0) ? NINF : 0.0f;
        __syncthreads();

        int kk = t >> 4;            // [0,16): k-row within chunk
        int c0 = (t & 15) * 4;      // channel quad start
        float s[4], s2[4], a0[4], a1[4], a2[4];
#pragma unroll
        for (int u = 0; u < 4; ++u) { s[u] = 0.f; s2[u] = 0.f; a0[u] = 0.f; a1[u] = 0.f; a2[u] = 0.f; }

        // chunk j covers rows 16j..16j+15; this thread's row = kk + 16j
        const float* mptr = equi_msg + (size_t)bq * 16384 + kk * 64 + c0;  // +1024*j
        const u16*   pptr = proj_equi + (size_t)b * 49152 + kk * 192 + c0; // +3072*j

        float4 mA, mB, mC, mD;
        uint2 pA0, pA1, pA2, pB0, pB1, pB2, pC0, pC1, pC2, pD0, pD1, pD2;

#define LOADSLOT(S_, j_) do {                                   \
        m##S_ = *(const float4*)(mptr + (j_) * 1024);           \
        const u16* pb_ = pptr + (j_) * 3072;                    \
        p##S_##0 = *(const uint2*)(pb_);                        \
        p##S_##1 = *(const uint2*)(pb_ + 64);                   \
        p##S_##2 = *(const uint2*)(pb_ + 128);                  \
    } while (0)

#define CONSUME(S_, j_) do {                                    \
        float mk_ = S.e.maskv[(j_) * 16 + kk];                  \
        float mv_[4], p0_[4], p1_[4], p2_[4];                   \
        mv_[0] = m##S_.x; mv_[1] = m##S_.y;                     \
        mv_[2] = m##S_.z; mv_[3] = m##S_.w;                     \
        unpack4(p##S_##0, p0_); unpack4(p##S_##1, p1_);         \
        unpack4(p##S_##2, p2_);                                 \
        _Pragma("unroll")                                       \
        for (int u = 0; u < 4; ++u) {                           \
            float e_ = __expf(mv_[u] + mk_);                    \
            s[u]  += e_;                                        \
            s2[u] += e_ * e_;                                   \
            a0[u] += e_ * p0_[u];                               \
            a1[u] += e_ * p1_[u];                               \
            a2[u] += e_ * p2_[u];                               \
        }                                                       \
    } while (0)

        LOADSLOT(A, 0); LOADSLOT(B, 1); LOADSLOT(C, 2); LOADSLOT(D, 3);

#pragma unroll 1
        for (int jj = 0; jj < 3; ++jj) {
            int j = jj * 4;
            CONSUME(A, j + 0); LOADSLOT(A, j + 4);
            CONSUME(B, j + 1); LOADSLOT(B, j + 5);
            CONSUME(C, j + 2); LOADSLOT(C, j + 6);
            CONSUME(D, j + 3); LOADSLOT(D, j + 7);
        }
        CONSUME(A, 12); CONSUME(B, 13); CONSUME(C, 14); CONSUME(D, 15);

#undef LOADSLOT
#undef CONSUME

        // ---- reduce over kk within wave: butterfly across lane bits 4..5
#pragma unroll
        for (int msk = 16; msk <= 32; msk <<= 1) {
#pragma unroll
            for (int u = 0; u < 4; ++u) {
                s[u]  += __shfl_xor(s[u],  msk);
                s2[u] += __shfl_xor(s2[u], msk);
                a0[u] += __shfl_xor(a0[u], msk);
                a1[u] += __shfl_xor(a1[u], msk);
                a2[u] += __shfl_xor(a2[u], msk);
            }
        }
        {
            int w = t >> 6;
            if ((t & 63) < 16) {    // lane l<16 holds wave-sum for c = l*4..l*4+3
#pragma unroll
                for (int u = 0; u < 4; ++u) {
                    S.e.wp[w][0][c0 + u] = s[u];
                    S.e.wp[w][1][c0 + u] = s2[u];
                    S.e.wp[w][2][c0 + u] = a0[u];
                    S.e.wp[w][3][c0 + u] = a1[u];
                    S.e.wp[w][4][c0 + u] = a2[u];
                }
            }
        }
        __syncthreads();
        if (t < 192) {
            int d = t >> 6, c = t & 63;
            float ssum = 0.f, s2sum = 0.f, asum = 0.f;
#pragma unroll
            for (int w = 0; w < 4; ++w) {
                ssum  += S.e.wp[w][0][c];
                s2sum += S.e.wp[w][1][c];
                asum  += S.e.wp[w][2 + d][c];
            }
            float scale = sqrtf(s2sum) / (ssum * ssum);
            S.e.out_s[d][c] = asum * scale;
        }
        __syncthreads();
        if (t < 192) {
            int d = t >> 6, o = t & 63;
            float acc = b_eo[o];
            const float* wr = W_eo + o * 64;
#pragma unroll
            for (int c4 = 0; c4 < 64; c4 += 4) {
                float4 w = *(const float4*)(wr + c4);
                acc += S.e.out_s[d][c4 + 0] * w.x;
                acc += S.e.out_s[d][c4 + 1] * w.y;
                acc += S.e.out_s[d][c4 + 2] * w.z;
                acc += S.e.out_s[d][c4 + 3] * w.w;
            }
            out[(size_t)bq * 192 + t] = acc;
        }
    } else {
        // ================= proj_inv GEMM: 8 rows/block, coalesced WT_in ====
        int r0 = (blockIdx.x - 2048) * 8;
#pragma unroll
        for (int i = 0; i < 8; ++i)
            S.p.Xs[i][t] = v_inv[(size_t)(r0 + i) * 256 + t];
        __syncthreads();
        float acc[8];
        float bv = b_in[t];
#pragma unroll
        for (int r = 0; r < 8; ++r) acc[r] = bv;
#pragma unroll 8
        for (int i = 0; i < 256; ++i) {
            float w = WT_in[i * 256 + t];     // lane-consecutive: coalesced
#pragma unroll
            for (int r = 0; r < 8; ++r) acc[r] += S.p.Xs[r][i] * w;
        }
#pragma unroll
        for (int r = 0; r < 8; ++r)
            proj_inv[(size_t)(r0 + r) * 256 + t] = f2bf(acc[r]);
    }
}

// ---------------------------------------------------------------------------
// Inv attention, 2 q-rows per block (grid 1024) — round-0 validated body.
// ---------------------------------------------------------------------------
__global__ __launch_bounds__(256) void k_inv_attn2(
    const float* __restrict__ inv_msg,  // [B,256,256,16] fp32
    const int* __restrict__ adj,        // [B,256,256]
    const u16* __restrict__ proj,       // [B,256,256] bf16 (ws)
    float* __restrict__ out_rows)       // [2048,256] fp32 (ws)
{
    int bq2 = blockIdx.x;               // [0,1024), 2 q's each
    int b = bq2 >> 7;
    int t = threadIdx.x;

    __shared__ float maskv[2][256];
    __shared__ int anyflag[2];
    __shared__ float p_s[2][256][16];
    __shared__ float spart[2][16][16], s2part[2][16][16];
    __shared__ float sh_s[2][16], sh_s2[2][16];
    __shared__ float red[4][2][256];

    if (t < 2) anyflag[t] = 0;
    __syncthreads();
    int a0 = adj[((size_t)bq2 * 2 + 0) * 256 + t];
    int a1 = adj[((size_t)bq2 * 2 + 1) * 256 + t];
    if (a0 != 0) anyflag[0] = 1;
    if (a1 != 0) anyflag[1] = 1;
    __syncthreads();
    maskv[0][t] = (a0 == 0 && anyflag[0] != 0) ? NINF : 0.0f;
    maskv[1][t] = (a1 == 0 && anyflag[1] != 0) ? NINF : 0.0f;
    __syncthreads();

    // pass 1: exps + per-head s, s2 partials
    {
        int h = t & 15, kk = t >> 4;
#pragma unroll
        for (int q = 0; q < 2; ++q) {
            const float* mb = inv_msg + ((size_t)bq2 * 2 + q) * 4096;
            float ss = 0.f, ss2 = 0.f;
#pragma unroll
            for (int j = 0; j < 16; ++j) {
                int k = kk + 16 * j;
                float e = __expf(mb[k * 16 + h] + maskv[q][k]);
                p_s[q][k][h] = e;
                ss += e; ss2 += e * e;
            }
            spart[q][kk][h] = ss;
            s2part[q][kk][h] = ss2;
        }
    }
    __syncthreads();
    if (t < 64) {
        int q = t >> 5, sel = (t >> 4) & 1, h = t & 15;
        float sum = 0.f;
        if (sel == 0) {
#pragma unroll
            for (int kk = 0; kk < 16; ++kk) sum += spart[q][kk][h];
            sh_s[q][h] = sum;
        } else {
#pragma unroll
            for (int kk = 0; kk < 16; ++kk) sum += s2part[q][kk][h];
            sh_s2[q][h] = sum;
        }
    }
    __syncthreads();

    // pass 2: out_i[q,h,e] = sum_k p[q,k,h] * proj[b,k,h*16+e]
    {
        int kk2 = t >> 6, h = (t >> 2) & 15, eg = t & 3;
        float acc0[4] = {0.f, 0.f, 0.f, 0.f};
        float acc1[4] = {0.f, 0.f, 0.f, 0.f};
        const u16* pb = proj + (size_t)b * 65536 + h * 16 + eg * 4;
        for (int j = 0; j < 64; ++j) {
            int k = kk2 + 4 * j;
            uint2 u = *(const uint2*)(pb + (size_t)k * 256);
            float w[4]; unpack4(u, w);
            float pq0 = p_s[0][k][h];
            float pq1 = p_s[1][k][h];
#pragma unroll
            for (int ii = 0; ii < 4; ++ii) {
                acc0[ii] += pq0 * w[ii];
                acc1[ii] += pq1 * w[ii];
            }
        }
#pragma unroll
        for (int ii = 0; ii < 4; ++ii) {
            red[kk2][0][h * 16 + eg * 4 + ii] = acc0[ii];
            red[kk2][1][h * 16 + eg * 4 + ii] = acc1[ii];
        }
    }
    __syncthreads();
    {
        int h = t >> 4;
#pragma unroll
        for (int q = 0; q < 2; ++q) {
            float sum = red[0][q][t] + red[1][q][t] + red[2][q][t] + red[3][q][t];
            float sv = sh_s[q][h];
            out_rows[((size_t)bq2 * 2 + q) * 256 + t] = sum * sqrtf(sh_s2[q][h]) / (sv * sv);
        }
    }
}

// ---------------------------------------------------------------------------
// Final epilogue GEMM with transposed weights: Y[r,o] = sum_i X[r,i]*WT[i,o]+b
// ---------------------------------------------------------------------------
__global__ __launch_bounds__(256) void k_rowgemm_tof32(
    const float* __restrict__ X,     // [2048, 256] fp32 (ws)
    const float* __restrict__ WT,    // [256, 256] (i,o) ws
    const float* __restrict__ bias,  // [256]
    float* __restrict__ Y)           // [2048, 256] fp32
{
    int r0 = blockIdx.x * 8;
    int t = threadIdx.x;
    __shared__ float Xs[8][256];
#pragma unroll
    for (int i = 0; i < 8; ++i)
        Xs[i][t] = X[(size_t)(r0 + i) * 256 + t];
    __syncthreads();
    float acc[8];
    float bv = bias[t];
#pragma unroll
    for (int r = 0; r < 8; ++r) acc[r] = bv;
#pragma unroll 8
    for (int i = 0; i < 256; ++i) {
        float w = WT[i * 256 + t];           // lane-consecutive: coalesced
#pragma unroll
        for (int r = 0; r < 8; ++r) acc[r] += Xs[r][i] * w;
    }
#pragma unroll
    for (int r = 0; r < 8; ++r)
        Y[(size_t)(r0 + r) * 256 + t] = acc[r];
}

// ---------------------------------------------------------------------------
extern "C" void kernel_launch(void* const* d_in, const int* in_sizes, int n_in,
                              void* d_out, int out_size, void* d_ws, size_t ws_size,
                              hipStream_t stream) {
    (void)in_sizes; (void)n_in; (void)out_size; (void)ws_size;

    const float* v_equi   = (const float*)d_in[0];
    const float* v_inv    = (const float*)d_in[1];
    const float* equi_msg = (const float*)d_in[2];
    const float* inv_msg  = (const float*)d_in[3];
    const int*   adj      = (const int*)d_in[4];
    const float* W_coord  = (const float*)d_in[5];
    const float* W_eo     = (const float*)d_in[6];
    const float* b_eo     = (const float*)d_in[7];
    const float* W_in     = (const float*)d_in[8];
    const float* b_in     = (const float*)d_in[9];
    const float* W_out    = (const float*)d_in[10];
    const float* b_out    = (const float*)d_in[11];
    float* out = (float*)d_out;

    char* ws = (char*)d_ws;
    u16*   proj_equi = (u16*)(ws);                   // 786432 B
    u16*   proj_inv  = (u16*)(ws + 786432);          // 1048576 B -> ends 1835008
    float* WT_out    = (float*)(ws + 1835008);       // 262144 B  -> ends 2097152
    float* WT_in     = (float*)(ws + 2097152);       // 262144 B  -> ends 2359296
    float* out_rows  = (float*)(ws + 2359296);       // 2097152 B -> ends 4456448

    k_setup<<<dim3(416), dim3(256), 0, stream>>>(
        W_out, WT_out, W_in, WT_in, v_equi, W_coord, proj_equi);
    k_equi_proj<<<dim3(2304), dim3(256), 0, stream>>>(
        equi_msg, adj, proj_equi, W_eo, b_eo, out,
        v_inv, WT_in, b_in, proj_inv);
    k_inv_attn2<<<dim3(1024), dim3(256), 0, stream>>>(
        inv_msg, adj, proj_inv, out_rows);
    k_rowgemm_tof32<<<dim3(256), dim3(256), 0, stream>>>(
        out_rows, WT_out, b_out, out + 393216);
}